// Round 1
// baseline (113.198 us; speedup 1.0000x reference)
//
#include <hip/hip_runtime.h>

// out[b,m,p] = add[m,p] + (m<IN && p<IN ? x[b,m,p] : 0)
// B=512, IN=256, OUT=400. Pure streaming: 327.7MB write + 134.2MB read.

constexpr int B   = 512;
constexpr int IN  = 256;
constexpr int OUT = 400;
constexpr int P4  = OUT / 4;   // 100 float4 per output row
constexpr int X4  = IN / 4;    // 64 float4 per x row

__global__ __launch_bounds__(256) void spd_increase_dim_kernel(
    const float* __restrict__ x,
    const float* __restrict__ add,
    float* __restrict__ out)
{
    const int total  = B * OUT * P4;            // 20,480,000 float4s
    const int stride = gridDim.x * blockDim.x;
    for (int i = blockIdx.x * blockDim.x + threadIdx.x; i < total; i += stride) {
        int bm = i / P4;                        // b*OUT + m
        int p4 = i - bm * P4;
        int m  = bm % OUT;
        int b  = bm / OUT;

        // add row m is tiny (640KB total buffer) -> L2/L3 hit after warmup
        float4 v = *reinterpret_cast<const float4*>(add + m * OUT + p4 * 4);

        if (m < IN && p4 < X4) {
            const float4 xv = *reinterpret_cast<const float4*>(
                x + ((long)b * IN + m) * IN + p4 * 4);
            v.x += xv.x; v.y += xv.y; v.z += xv.z; v.w += xv.w;
        }

        *reinterpret_cast<float4*>(out + (long)bm * OUT + p4 * 4) = v;
    }
}

extern "C" void kernel_launch(void* const* d_in, const int* in_sizes, int n_in,
                              void* d_out, int out_size, void* d_ws, size_t ws_size,
                              hipStream_t stream)
{
    const float* x   = (const float*)d_in[0];  // [B, IN, IN]
    // d_in[1] is eye [OUT, IN] -- structurally the identity embedding; unused.
    const float* add = (const float*)d_in[2];  // [OUT, OUT]
    float* out = (float*)d_out;                // [B, OUT, OUT]

    const int threads = 256;
    const int blocks  = 2048;  // 256 CU x 8 blocks, grid-stride covers the rest
    spd_increase_dim_kernel<<<blocks, threads, 0, stream>>>(x, add, out);
}